// Round 3
// baseline (8268.109 us; speedup 1.0000x reference)
//
#include <hip/hip_runtime.h>
#include <cstdint>
#include <cstddef>
#include <math.h>

#define NROWS 65536
#define DIM   512
#define KCB   256
#define RPB   16    // rows per block
#define THR   512   // threads per block

// ---------------- Threefry-2x32 (jax partitionable; confirmed by R1 bulk match) ----------------
__host__ __device__ __forceinline__ uint32_t tf_rotl(uint32_t x, uint32_t r) {
  return (x << r) | (x >> (32u - r));
}
__host__ __device__ inline void tf2x32(uint32_t k0, uint32_t k1,
                                       uint32_t x0, uint32_t x1,
                                       uint32_t& o0, uint32_t& o1) {
  uint32_t k2 = k0 ^ k1 ^ 0x1BD11BDAu;
  x0 += k0; x1 += k1;
#define TF_R(r) { x0 += x1; x1 = tf_rotl(x1, r); x1 ^= x0; }
  TF_R(13) TF_R(15) TF_R(26) TF_R(6)
  x0 += k1; x1 += k2 + 1u;
  TF_R(17) TF_R(29) TF_R(16) TF_R(24)
  x0 += k2; x1 += k0 + 2u;
  TF_R(13) TF_R(15) TF_R(26) TF_R(6)
  x0 += k0; x1 += k1 + 3u;
  TF_R(17) TF_R(29) TF_R(16) TF_R(24)
  x0 += k1; x1 += k2 + 4u;
  TF_R(13) TF_R(15) TF_R(26) TF_R(6)
  x0 += k2; x1 += k0 + 5u;
#undef TF_R
  o0 = x0; o1 = x1;
}

// f32 gumbel, replicating np-f32: u from jax bits, then -log32(-log32(u)),
// each f32 log obtained by correctly-rounding the f64 log.
__device__ __forceinline__ float gumbel32(uint32_t k0, uint32_t k1, uint32_t j) {
  uint32_t o0, o1;
  tf2x32(k0, k1, 0u, j, o0, o1);
  uint32_t bits = o0 ^ o1;
  float f = __uint_as_float((bits >> 9) | 0x3f800000u) - 1.0f;
  if (f == 0.0f) f = 1.17549435e-38f;
  float t1 = (float)log((double)f);
  float t2 = (float)log((double)(-t1));
  return -t2;
}

__device__ __forceinline__ float exp32cr(float z) {
  return (float)exp((double)z);
}

// wave argmax: f32 value, smaller index wins ties (np first-occurrence)
__device__ __forceinline__ void argmax64(float& v, int& i) {
#pragma unroll
  for (int off = 32; off >= 1; off >>= 1) {
    float ov = __shfl_xor(v, off);
    int   oi = __shfl_xor(i, off);
    if (ov > v || (ov == v && oi < i)) { v = ov; i = oi; }
  }
}

// ---------------- cpd[i][d][k] = (C_i @ A_i)[k][d], seq-e FMA (BLAS order) ----------------
__global__ __launch_bounds__(256) void k_cproj(const float* __restrict__ C,
                                               const float* __restrict__ A,
                                               float* __restrict__ cpd) {
  const int i = blockIdx.x >> 6;
  const int d0 = (blockIdx.x & 63) * 8;
  const int t = threadIdx.x;          // t = k
  const float* Ai = A + (size_t)i * DIM * DIM;
  const float* Ci = C + (size_t)i * KCB * DIM;
  float acc[8] = {};
  for (int e = 0; e < DIM; ++e) {
    float cv = Ci[(size_t)t * DIM + e];
#pragma unroll
    for (int dd = 0; dd < 8; ++dd)
      acc[dd] = fmaf(cv, Ai[(size_t)e * DIM + d0 + dd], acc[dd]);
  }
#pragma unroll
  for (int dd = 0; dd < 8; ++dd)
    cpd[((size_t)i * DIM + d0 + dd) * KCB + t] = acc[dd];
}

// ---------------- Per-stage fused, small-LDS version (3 blocks/CU target) ----------------
// LDS: xrow[16][512] (32KB, live whole kernel) + xph[16][256] (16KB) which serves as:
//   xproj d-half / logits lg / exp ssbuf (in-place over lg) / pbuf d-half.
// xproj+logits and pbuf+xupdate are each computed in two d-halves; per-(n,k)/(n,e)
// accumulation order over d remains strictly 0..511 sequential (bit-exact).
__global__ __launch_bounds__(THR, 6) void k_stage(
    const float* __restrict__ Xin,    // stage input x rows
    float* __restrict__ Xout,         // stage output x rows (stage<3); own-rows in-place safe
    const float* __restrict__ Ai,     // W_att[i] [512][512]
    const float* __restrict__ cpdi,   // cproj^T  [512 d][256 k]
    const float* __restrict__ Cbi,    // codebooks[i] [256][512]
    const float* __restrict__ Wr,     // W_rnn [512][512]
    float* __restrict__ out,
    uint32_t kh0, uint32_t kh1, uint32_t ks0, uint32_t ks1, int stage) {
  __shared__ __align__(16) float xrow[RPB * 512];
  __shared__ __align__(16) float xph[RPB * 256];
  __shared__ int selL[RPB]; __shared__ int idxL[RPB]; __shared__ float wsL[RPB];
  const int t = threadIdx.x;
  const int n0 = blockIdx.x * RPB;

  // stage x rows (float4, coalesced)
  {
    const float4* src = (const float4*)(Xin + (size_t)n0 * 512);
    float4* dst = (float4*)xrow;
#pragma unroll
    for (int q = 0; q < 4; ++q) dst[q * 512 + t] = src[q * 512 + t];
  }
  __syncthreads();

  const int tg = t >> 7;       // 4 row-groups of 4 rows
  const int tc = t & 127;
  const int r0 = tg * 4;

  // logits accumulator persists across the two d-halves (order d=0..511 per k)
  float lacc[4][2];
#pragma unroll
  for (int rr = 0; rr < 4; ++rr) { lacc[rr][0] = 0.0f; lacc[rr][1] = 0.0f; }

#pragma unroll 1
  for (int hp = 0; hp < 2; ++hp) {
    // ph0b-half: xp[n][d] = seq-e FMA of x[n][e]*A[e][d], d in [hp*256, hp*256+256)
    {
      const int d0 = hp * 256 + tc * 2;
      float acc[4][2];
#pragma unroll
      for (int rr = 0; rr < 4; ++rr) { acc[rr][0] = 0.0f; acc[rr][1] = 0.0f; }
      for (int e = 0; e < 512; e += 4) {
        float2 a0 = *(const float2*)&Ai[(size_t)(e + 0) * 512 + d0];
        float2 a1 = *(const float2*)&Ai[(size_t)(e + 1) * 512 + d0];
        float2 a2 = *(const float2*)&Ai[(size_t)(e + 2) * 512 + d0];
        float2 a3 = *(const float2*)&Ai[(size_t)(e + 3) * 512 + d0];
#pragma unroll
        for (int rr = 0; rr < 4; ++rr) {
          float4 xv = *(const float4*)&xrow[(r0 + rr) * 512 + e];
          acc[rr][0] = fmaf(xv.x, a0.x, acc[rr][0]);
          acc[rr][1] = fmaf(xv.x, a0.y, acc[rr][1]);
          acc[rr][0] = fmaf(xv.y, a1.x, acc[rr][0]);
          acc[rr][1] = fmaf(xv.y, a1.y, acc[rr][1]);
          acc[rr][0] = fmaf(xv.z, a2.x, acc[rr][0]);
          acc[rr][1] = fmaf(xv.z, a2.y, acc[rr][1]);
          acc[rr][0] = fmaf(xv.w, a3.x, acc[rr][0]);
          acc[rr][1] = fmaf(xv.w, a3.y, acc[rr][1]);
        }
      }
      // write this d-half (prior half's reads finished at the trailing sync below)
#pragma unroll
      for (int rr = 0; rr < 4; ++rr)
        *(float2*)&xph[(r0 + rr) * 256 + tc * 2] = make_float2(acc[rr][0], acc[rr][1]);
    }
    __syncthreads();

    // ph1-half: lacc[n][k] += seq-d (mul,add) over d in this half (np.einsum order)
    {
      const int k0 = tc * 2;
      for (int dl = 0; dl < 256; dl += 4) {
        const int d = hp * 256 + dl;
        float2 c0 = *(const float2*)&cpdi[(size_t)(d + 0) * 256 + k0];
        float2 c1 = *(const float2*)&cpdi[(size_t)(d + 1) * 256 + k0];
        float2 c2 = *(const float2*)&cpdi[(size_t)(d + 2) * 256 + k0];
        float2 c3 = *(const float2*)&cpdi[(size_t)(d + 3) * 256 + k0];
#pragma unroll
        for (int rr = 0; rr < 4; ++rr) {
          float4 xv = *(const float4*)&xph[(r0 + rr) * 256 + dl];
          lacc[rr][0] = __fadd_rn(lacc[rr][0], __fmul_rn(xv.x, c0.x));
          lacc[rr][1] = __fadd_rn(lacc[rr][1], __fmul_rn(xv.x, c0.y));
          lacc[rr][0] = __fadd_rn(lacc[rr][0], __fmul_rn(xv.y, c1.x));
          lacc[rr][1] = __fadd_rn(lacc[rr][1], __fmul_rn(xv.y, c1.y));
          lacc[rr][0] = __fadd_rn(lacc[rr][0], __fmul_rn(xv.z, c2.x));
          lacc[rr][1] = __fadd_rn(lacc[rr][1], __fmul_rn(xv.z, c2.y));
          lacc[rr][0] = __fadd_rn(lacc[rr][0], __fmul_rn(xv.w, c3.x));
          lacc[rr][1] = __fadd_rn(lacc[rr][1], __fmul_rn(xv.w, c3.y));
        }
      }
    }
    __syncthreads();   // all xph reads of this half done
  }

  // write logits lg[16][256] into xph
  {
    const int k0 = tc * 2;
#pragma unroll
    for (int rr = 0; rr < 4; ++rr)
      *(float2*)&xph[(r0 + rr) * 256 + k0] = make_float2(lacc[rr][0], lacc[rr][1]);
  }
  __syncthreads();

  // ph2: per-row decisions (wave owns 2 rows; lane c owns k = sub*64+c).
  // ssbuf overlays lg IN PLACE: each location read and then written by the same thread.
  {
    float* lgb   = xph;
    float* ssbuf = xph;
    const int c = t & 63;
#pragma unroll 1
    for (int rr2 = 0; rr2 < 2; ++rr2) {
      const int r = (t >> 6) * 2 + rr2;
      const int n = n0 + r;
      const uint32_t jb = (uint32_t)n * 256u;
      float l[4];
#pragma unroll
      for (int sub = 0; sub < 4; ++sub) l[sub] = lgb[r * 256 + sub * 64 + c];
      // idx: first-max over f32 logits
      float bv = l[0]; int bi = c;
#pragma unroll
      for (int sub = 1; sub < 4; ++sub)
        if (l[sub] > bv) { bv = l[sub]; bi = sub * 64 + c; }
      argmax64(bv, bi);
      // hard sel: first-max over (l+g_hard)/0.9f
      float sv = 0.0f; int si = 0;
#pragma unroll
      for (int sub = 0; sub < 4; ++sub) {
        float g = gumbel32(kh0, kh1, jb + (uint32_t)(sub * 64 + c));
        float s = __fdiv_rn(__fadd_rn(l[sub], g), 0.9f);
        if (sub == 0 || s > sv) { sv = s; si = sub * 64 + c; }
      }
      argmax64(sv, si);
      // soft: scores, row max, exp (CR f32)
      float ssv[4];
#pragma unroll
      for (int sub = 0; sub < 4; ++sub) {
        float g = gumbel32(ks0, ks1, jb + (uint32_t)(sub * 64 + c));
        ssv[sub] = __fdiv_rn(__fadd_rn(l[sub], g), 0.9f);
      }
      float m = fmaxf(fmaxf(ssv[0], ssv[1]), fmaxf(ssv[2], ssv[3]));
#pragma unroll
      for (int off = 32; off >= 1; off >>= 1) m = fmaxf(m, __shfl_xor(m, off));
#pragma unroll
      for (int sub = 0; sub < 4; ++sub)
        ssbuf[r * 256 + sub * 64 + c] = exp32cr(__fsub_rn(ssv[sub], m));
      if (c == 0) { selL[r] = si; idxL[r] = bi; }
    }
  }
  __syncthreads();

  // ph2b: numpy-pairwise softmax denom, parallel over 16 rows x 2 halves x 8 accs.
  // Exact pw128 order: acc_j = a[j]+a[8+j]+...+a[120+j] (15 seq adds), then tree
  // ((r0+r1)+(r2+r3))+((r4+r5)+(r6+r7)) via shfl_xor(1,2,4); halves via shfl_xor(8).
  if (t < 256) {
    const int r = t >> 4, h = (t >> 3) & 1, j = t & 7;
    const float* a = xph + r * 256 + h * 128 + j;
    float acc = a[0];
#pragma unroll
    for (int i = 1; i < 16; ++i) acc = __fadd_rn(acc, a[8 * i]);
    float s = __fadd_rn(acc, __shfl_xor(acc, 1));
    s = __fadd_rn(s, __shfl_xor(s, 2));
    s = __fadd_rn(s, __shfl_xor(s, 4));
    float S = __fadd_rn(s, __shfl_xor(s, 8));   // h=0 lane: half0 + half1 (ref order)
    if ((t & 15) == 0) {
      const int n = n0 + r;
      int sel = selL[r];
      float wsv = __fdiv_rn(xph[r * 256 + sel], S);
      wsL[r] = __fadd_rn(__fsub_rn(1.0f, wsv), wsv);
      out[(size_t)NROWS * DIM + (size_t)n * 4 + stage] = (float)idxL[r];
    }
  }
  __syncthreads();

  // ph3-RMW: out_sum accumulate, p = fl32(wstar * C[sel][col]), ref add order
#pragma unroll 4
  for (int r = 0; r < RPB; ++r) {
    float p = __fmul_rn(wsL[r], Cbi[(size_t)selL[r] * 512 + t]);
    size_t o = (size_t)(n0 + r) * 512 + t;
    out[o] = (stage == 0) ? p : __fadd_rn(out[o], p);
  }

  // ph3/ph4 halves: pbuf-half = p[:, hp*256:+256] in xph; x-update accumulates over d
  if (stage < 3) {
    float acc4[4][4];
#pragma unroll
    for (int rr = 0; rr < 4; ++rr)
#pragma unroll
      for (int c = 0; c < 4; ++c) acc4[rr][c] = 0.0f;

#pragma unroll 1
    for (int hp = 0; hp < 2; ++hp) {
      {
        const int cc = t & 255;
        const int rb = t >> 8;
#pragma unroll
        for (int rr2 = 0; rr2 < 8; ++rr2) {
          const int r = rr2 * 2 + rb;
          xph[r * 256 + cc] =
              __fmul_rn(wsL[r], Cbi[(size_t)selL[r] * 512 + hp * 256 + cc]);
        }
      }
      __syncthreads();
      {
        const int e0 = tc * 4;
        for (int dl = 0; dl < 256; dl += 4) {
          const int d = hp * 256 + dl;
          float4 w0 = *(const float4*)&Wr[(size_t)(d + 0) * 512 + e0];
          float4 w1 = *(const float4*)&Wr[(size_t)(d + 1) * 512 + e0];
          float4 w2 = *(const float4*)&Wr[(size_t)(d + 2) * 512 + e0];
          float4 w3 = *(const float4*)&Wr[(size_t)(d + 3) * 512 + e0];
#pragma unroll
          for (int rr = 0; rr < 4; ++rr) {
            float4 pv = *(const float4*)&xph[(r0 + rr) * 256 + dl];
            acc4[rr][0] = fmaf(pv.x, w0.x, acc4[rr][0]);
            acc4[rr][1] = fmaf(pv.x, w0.y, acc4[rr][1]);
            acc4[rr][2] = fmaf(pv.x, w0.z, acc4[rr][2]);
            acc4[rr][3] = fmaf(pv.x, w0.w, acc4[rr][3]);
            acc4[rr][0] = fmaf(pv.y, w1.x, acc4[rr][0]);
            acc4[rr][1] = fmaf(pv.y, w1.y, acc4[rr][1]);
            acc4[rr][2] = fmaf(pv.y, w1.z, acc4[rr][2]);
            acc4[rr][3] = fmaf(pv.y, w1.w, acc4[rr][3]);
            acc4[rr][0] = fmaf(pv.z, w2.x, acc4[rr][0]);
            acc4[rr][1] = fmaf(pv.z, w2.y, acc4[rr][1]);
            acc4[rr][2] = fmaf(pv.z, w2.z, acc4[rr][2]);
            acc4[rr][3] = fmaf(pv.z, w2.w, acc4[rr][3]);
            acc4[rr][0] = fmaf(pv.w, w3.x, acc4[rr][0]);
            acc4[rr][1] = fmaf(pv.w, w3.y, acc4[rr][1]);
            acc4[rr][2] = fmaf(pv.w, w3.z, acc4[rr][2]);
            acc4[rr][3] = fmaf(pv.w, w3.w, acc4[rr][3]);
          }
        }
      }
      __syncthreads();   // pbuf reads done before next half's store
    }

    // final: x_next = x - p@Wr, write to global (own rows; in-place safe)
    const int e0 = tc * 4;
#pragma unroll
    for (int rr = 0; rr < 4; ++rr) {
      const int rw = r0 + rr;
      float4 xv = *(const float4*)&xrow[rw * 512 + e0];
      float4 o;
      o.x = __fsub_rn(xv.x, acc4[rr][0]);
      o.y = __fsub_rn(xv.y, acc4[rr][1]);
      o.z = __fsub_rn(xv.z, acc4[rr][2]);
      o.w = __fsub_rn(xv.w, acc4[rr][3]);
      *(float4*)&Xout[(size_t)(n0 + rw) * 512 + e0] = o;
    }
  }
}

extern "C" void kernel_launch(void* const* d_in, const int* in_sizes, int n_in,
                              void* d_out, int out_size, void* d_ws, size_t ws_size,
                              hipStream_t stream) {
  const float* x  = (const float*)d_in[0];   // [65536,512]
  const float* Cb = (const float*)d_in[1];   // [4,256,512]
  const float* A  = (const float*)d_in[2];   // [4,512,512]
  const float* Wr = (const float*)d_in[3];   // [512,512]
  float* out = (float*)d_out;
  float* ws  = (float*)d_ws;

  float* cpd  = ws;                          // 4*512*256 = 524288 f (2 MB)
  float* xcur = ws + 524288;                 // 65536*512 f (134 MB)

  // keys: fold_in(key(42), i) -> split -> (k_soft = keys[0], k_hard = keys[1])
  uint32_t kh[4][2], ks[4][2];
  for (uint32_t i = 0; i < 4; ++i) {
    uint32_t f0, f1, a0, a1, b0, b1;
    tf2x32(0u, 42u, 0u, i, f0, f1);
    tf2x32(f0, f1, 0u, 0u, a0, a1);   // keys[0] -> k_soft
    tf2x32(f0, f1, 0u, 1u, b0, b1);   // keys[1] -> k_hard
    ks[i][0] = a0; ks[i][1] = a1;
    kh[i][0] = b0; kh[i][1] = b1;
  }

  k_cproj<<<dim3(256), dim3(256), 0, stream>>>(Cb, A, cpd);

  const int NB = NROWS / RPB;  // 4096
  for (int i = 0; i < 4; ++i) {
    const float* Xi = (i == 0) ? x : xcur;
    k_stage<<<dim3(NB), dim3(THR), 0, stream>>>(
        Xi, xcur, A + (size_t)i * DIM * DIM, cpd + (size_t)i * DIM * KCB,
        Cb + (size_t)i * KCB * DIM, Wr, out,
        kh[i][0], kh[i][1], ks[i][0], ks[i][1], i);
  }
}

// Round 4
// 6646.480 us; speedup vs baseline: 1.2440x; 1.2440x over previous
//
#include <hip/hip_runtime.h>
#include <cstdint>
#include <cstddef>
#include <math.h>

#define NROWS 65536
#define DIM   512
#define KCB   256
#define RPB   16    // rows per block (4 waves x 4 rows)
#define THR   256   // threads per block

// ---------------- Threefry-2x32 (jax partitionable; confirmed by R1 bulk match) ----------------
__host__ __device__ __forceinline__ uint32_t tf_rotl(uint32_t x, uint32_t r) {
  return (x << r) | (x >> (32u - r));
}
__host__ __device__ inline void tf2x32(uint32_t k0, uint32_t k1,
                                       uint32_t x0, uint32_t x1,
                                       uint32_t& o0, uint32_t& o1) {
  uint32_t k2 = k0 ^ k1 ^ 0x1BD11BDAu;
  x0 += k0; x1 += k1;
#define TF_R(r) { x0 += x1; x1 = tf_rotl(x1, r); x1 ^= x0; }
  TF_R(13) TF_R(15) TF_R(26) TF_R(6)
  x0 += k1; x1 += k2 + 1u;
  TF_R(17) TF_R(29) TF_R(16) TF_R(24)
  x0 += k2; x1 += k0 + 2u;
  TF_R(13) TF_R(15) TF_R(26) TF_R(6)
  x0 += k0; x1 += k1 + 3u;
  TF_R(17) TF_R(29) TF_R(16) TF_R(24)
  x0 += k1; x1 += k2 + 4u;
  TF_R(13) TF_R(15) TF_R(26) TF_R(6)
  x0 += k2; x1 += k0 + 5u;
#undef TF_R
  o0 = x0; o1 = x1;
}

// f32 gumbel, replicating np-f32: u from jax bits, then -log32(-log32(u)),
// each f32 log obtained by correctly-rounding the f64 log.
__device__ __forceinline__ float gumbel32(uint32_t k0, uint32_t k1, uint32_t j) {
  uint32_t o0, o1;
  tf2x32(k0, k1, 0u, j, o0, o1);
  uint32_t bits = o0 ^ o1;
  float f = __uint_as_float((bits >> 9) | 0x3f800000u) - 1.0f;
  if (f == 0.0f) f = 1.17549435e-38f;
  float t1 = (float)log((double)f);
  float t2 = (float)log((double)(-t1));
  return -t2;
}

__device__ __forceinline__ float exp32cr(float z) {
  return (float)exp((double)z);
}

// wave argmax: f32 value, smaller index wins ties (np first-occurrence)
__device__ __forceinline__ void argmax64(float& v, int& i) {
#pragma unroll
  for (int off = 32; off >= 1; off >>= 1) {
    float ov = __shfl_xor(v, off);
    int   oi = __shfl_xor(i, off);
    if (ov > v || (ov == v && oi < i)) { v = ov; i = oi; }
  }
}

// broadcast one lane's float to all lanes via SGPR (uniform lane index)
__device__ __forceinline__ float rdlane(float v, int lane) {
  return __int_as_float(__builtin_amdgcn_readlane(__float_as_int(v), lane));
}

// ---------------- cpd[i][d][k] = (C_i @ A_i)[k][d], seq-e FMA (BLAS order) ----------------
__global__ __launch_bounds__(256) void k_cproj(const float* __restrict__ C,
                                               const float* __restrict__ A,
                                               float* __restrict__ cpd) {
  const int i = blockIdx.x >> 6;
  const int d0 = (blockIdx.x & 63) * 8;
  const int t = threadIdx.x;          // t = k
  const float* Ai = A + (size_t)i * DIM * DIM;
  const float* Ci = C + (size_t)i * KCB * DIM;
  float acc[8] = {};
  for (int e = 0; e < DIM; ++e) {
    float cv = Ci[(size_t)t * DIM + e];
#pragma unroll
    for (int dd = 0; dd < 8; ++dd)
      acc[dd] = fmaf(cv, Ai[(size_t)e * DIM + d0 + dd], acc[dd]);
  }
#pragma unroll
  for (int dd = 0; dd < 8; ++dd)
    cpd[((size_t)i * DIM + d0 + dd) * KCB + t] = acc[dd];
}

// ---------------- Per-stage, register-resident GEMMs with readlane broadcast ----------------
// Each wave owns 4 rows. x / xproj / p live in the wave's registers (lane L holds
// element L*8+j); the sequential-K operand is broadcast with v_readlane into an SGPR
// consumed by v_fmac — ZERO LDS traffic in the GEMM phases (R2's LDS pipe was the
// 1.5x bottleneck there). LDS holds only the 16KB logit/exp buffer for ph2/ph2b.
// All accumulation orders (strict ascending K per output, mul/add split in ph1)
// preserved bit-exact; ph2/ph2b/ph3 bodies are the R2/R3-verified ones.
__global__ __launch_bounds__(THR, 4) void k_stage(
    const float* __restrict__ Xin,    // stage input x rows
    float* __restrict__ Xout,         // stage output x rows (stage<3); own-rows in-place safe
    const float* __restrict__ Ai,     // W_att[i] [512][512]
    const float* __restrict__ cpdi,   // cproj^T  [512 d][256 k]
    const float* __restrict__ Cbi,    // codebooks[i] [256][512]
    const float* __restrict__ Wr,     // W_rnn [512][512]
    float* __restrict__ out,
    uint32_t kh0, uint32_t kh1, uint32_t ks0, uint32_t ks1, int stage) {
  __shared__ __align__(16) float lgss[RPB * 256];   // logits, then exp (in-place)
  __shared__ int selL[RPB]; __shared__ int idxL[RPB]; __shared__ float wsL[RPB];
  const int t = threadIdx.x;
  const int L = t & 63;          // lane
  const int rb = (t >> 6) * 4;   // wave's rows: rb..rb+3
  const int n0 = blockIdx.x * RPB;

  // load wave's x rows into regs: xr[r][j] = x[n0+rb+r][L*8+j]
  float xr[4][8];
#pragma unroll
  for (int r = 0; r < 4; ++r) {
    const float* px = Xin + (size_t)(n0 + rb + r) * 512 + L * 8;
    float4 a = *(const float4*)px;
    float4 b = *(const float4*)(px + 4);
    xr[r][0] = a.x; xr[r][1] = a.y; xr[r][2] = a.z; xr[r][3] = a.w;
    xr[r][4] = b.x; xr[r][5] = b.y; xr[r][6] = b.z; xr[r][7] = b.w;
  }

  // ph0b: xp[n][d] = seq-e FMA of x[n][e]*A[e][d]; lane L accumulates d = L*8+c.
  float xp[4][8];
#pragma unroll
  for (int r = 0; r < 4; ++r)
#pragma unroll
    for (int c = 0; c < 8; ++c) xp[r][c] = 0.0f;
  for (int eb = 0; eb < 64; ++eb) {
#pragma unroll
    for (int j = 0; j < 8; ++j) {
      const int e = eb * 8 + j;
      const float* arow = Ai + (size_t)e * 512 + L * 8;
      float4 a0 = *(const float4*)arow;
      float4 a1 = *(const float4*)(arow + 4);
      float av[8] = {a0.x, a0.y, a0.z, a0.w, a1.x, a1.y, a1.z, a1.w};
      float xs[4];
#pragma unroll
      for (int r = 0; r < 4; ++r) xs[r] = rdlane(xr[r][j], eb);
#pragma unroll
      for (int r = 0; r < 4; ++r)
#pragma unroll
        for (int c = 0; c < 8; ++c)
          xp[r][c] = fmaf(xs[r], av[c], xp[r][c]);
    }
  }

  // ph1: logit[n][k] = seq-d (mul,add) of xp[n][d]*cpd[d][k]; lane L owns k = sub*64+L.
  // xp[r][d] broadcast from regs: value for d = db*8+j sits in lane db, reg xp[r][j].
  float lacc[4][4];
#pragma unroll
  for (int r = 0; r < 4; ++r)
#pragma unroll
    for (int s = 0; s < 4; ++s) lacc[r][s] = 0.0f;
  for (int db = 0; db < 64; ++db) {
#pragma unroll
    for (int j = 0; j < 8; ++j) {
      const int d = db * 8 + j;
      const float* cp = cpdi + (size_t)d * 256 + L;
      float c0 = cp[0], c1 = cp[64], c2 = cp[128], c3 = cp[192];
      float xs[4];
#pragma unroll
      for (int r = 0; r < 4; ++r) xs[r] = rdlane(xp[r][j], db);
#pragma unroll
      for (int r = 0; r < 4; ++r) {
        lacc[r][0] = __fadd_rn(lacc[r][0], __fmul_rn(xs[r], c0));
        lacc[r][1] = __fadd_rn(lacc[r][1], __fmul_rn(xs[r], c1));
        lacc[r][2] = __fadd_rn(lacc[r][2], __fmul_rn(xs[r], c2));
        lacc[r][3] = __fadd_rn(lacc[r][3], __fmul_rn(xs[r], c3));
      }
    }
  }
  // stash logits in LDS (k = sub*64+L layout matches ph2)
#pragma unroll
  for (int r = 0; r < 4; ++r)
#pragma unroll
    for (int s = 0; s < 4; ++s)
      lgss[(rb + r) * 256 + s * 64 + L] = lacc[r][s];
  __syncthreads();

  // ph2: per-row decisions (wave owns 4 rows; lane c owns k = sub*64+c).
  // exp values overwrite logits IN PLACE (same thread, same address — R3-verified).
  {
    float* lgb   = lgss;
    float* ssbuf = lgss;
    const int c = t & 63;
#pragma unroll 1
    for (int rr2 = 0; rr2 < 4; ++rr2) {
      const int r = (t >> 6) * 4 + rr2;
      const int n = n0 + r;
      const uint32_t jb = (uint32_t)n * 256u;
      float l[4];
#pragma unroll
      for (int sub = 0; sub < 4; ++sub) l[sub] = lgb[r * 256 + sub * 64 + c];
      // idx: first-max over f32 logits
      float bv = l[0]; int bi = c;
#pragma unroll
      for (int sub = 1; sub < 4; ++sub)
        if (l[sub] > bv) { bv = l[sub]; bi = sub * 64 + c; }
      argmax64(bv, bi);
      // hard sel: first-max over (l+g_hard)/0.9f
      float sv = 0.0f; int si = 0;
#pragma unroll
      for (int sub = 0; sub < 4; ++sub) {
        float g = gumbel32(kh0, kh1, jb + (uint32_t)(sub * 64 + c));
        float s = __fdiv_rn(__fadd_rn(l[sub], g), 0.9f);
        if (sub == 0 || s > sv) { sv = s; si = sub * 64 + c; }
      }
      argmax64(sv, si);
      // soft: scores, row max, exp (CR f32)
      float ssv[4];
#pragma unroll
      for (int sub = 0; sub < 4; ++sub) {
        float g = gumbel32(ks0, ks1, jb + (uint32_t)(sub * 64 + c));
        ssv[sub] = __fdiv_rn(__fadd_rn(l[sub], g), 0.9f);
      }
      float m = fmaxf(fmaxf(ssv[0], ssv[1]), fmaxf(ssv[2], ssv[3]));
#pragma unroll
      for (int off = 32; off >= 1; off >>= 1) m = fmaxf(m, __shfl_xor(m, off));
#pragma unroll
      for (int sub = 0; sub < 4; ++sub)
        ssbuf[r * 256 + sub * 64 + c] = exp32cr(__fsub_rn(ssv[sub], m));
      if (c == 0) { selL[r] = si; idxL[r] = bi; }
    }
  }
  __syncthreads();

  // ph2b: numpy-pairwise softmax denom, parallel over 16 rows x 2 halves x 8 accs
  // (R3-verified exact order). 256 threads cover all rows.
  {
    const int r = t >> 4, h = (t >> 3) & 1, j = t & 7;
    const float* a = lgss + r * 256 + h * 128 + j;
    float acc = a[0];
#pragma unroll
    for (int i = 1; i < 16; ++i) acc = __fadd_rn(acc, a[8 * i]);
    float s = __fadd_rn(acc, __shfl_xor(acc, 1));
    s = __fadd_rn(s, __shfl_xor(s, 2));
    s = __fadd_rn(s, __shfl_xor(s, 4));
    float S = __fadd_rn(s, __shfl_xor(s, 8));   // h=0 lane: half0 + half1 (ref order)
    if ((t & 15) == 0) {
      const int n = n0 + r;
      int sel = selL[r];
      float wsv = __fdiv_rn(lgss[r * 256 + sel], S);
      wsL[r] = __fadd_rn(__fsub_rn(1.0f, wsv), wsv);
      out[(size_t)NROWS * DIM + (size_t)n * 4 + stage] = (float)idxL[r];
    }
  }
  __syncthreads();

  // ph3: p = fl32(wstar * C[sel][col]) into regs; out_sum RMW (ref add order)
  float p[4][8];
#pragma unroll
  for (int r = 0; r < 4; ++r) {
    const int n = n0 + rb + r;
    const int sel = selL[rb + r];
    const float wv = wsL[rb + r];
    const float* crow = Cbi + (size_t)sel * 512 + L * 8;
    float4 c0 = *(const float4*)crow;
    float4 c1 = *(const float4*)(crow + 4);
    p[r][0] = __fmul_rn(wv, c0.x); p[r][1] = __fmul_rn(wv, c0.y);
    p[r][2] = __fmul_rn(wv, c0.z); p[r][3] = __fmul_rn(wv, c0.w);
    p[r][4] = __fmul_rn(wv, c1.x); p[r][5] = __fmul_rn(wv, c1.y);
    p[r][6] = __fmul_rn(wv, c1.z); p[r][7] = __fmul_rn(wv, c1.w);
    float* orow = out + (size_t)n * 512 + L * 8;
    if (stage == 0) {
      *(float4*)orow = make_float4(p[r][0], p[r][1], p[r][2], p[r][3]);
      *(float4*)(orow + 4) = make_float4(p[r][4], p[r][5], p[r][6], p[r][7]);
    } else {
      float4 o0 = *(const float4*)orow;
      float4 o1 = *(const float4*)(orow + 4);
      o0.x = __fadd_rn(o0.x, p[r][0]); o0.y = __fadd_rn(o0.y, p[r][1]);
      o0.z = __fadd_rn(o0.z, p[r][2]); o0.w = __fadd_rn(o0.w, p[r][3]);
      o1.x = __fadd_rn(o1.x, p[r][4]); o1.y = __fadd_rn(o1.y, p[r][5]);
      o1.z = __fadd_rn(o1.z, p[r][6]); o1.w = __fadd_rn(o1.w, p[r][7]);
      *(float4*)orow = o0;
      *(float4*)(orow + 4) = o1;
    }
  }

  // ph4: x_next = x - p @ W_rnn (seq-d FMA, d strictly ascending); p broadcast
  // from regs via readlane; x reloaded from global (caps live registers).
  if (stage < 3) {
    float a2[4][8];
#pragma unroll
    for (int r = 0; r < 4; ++r)
#pragma unroll
      for (int c = 0; c < 8; ++c) a2[r][c] = 0.0f;
    for (int db = 0; db < 64; ++db) {
#pragma unroll
      for (int j = 0; j < 8; ++j) {
        const int d = db * 8 + j;
        const float* wrow = Wr + (size_t)d * 512 + L * 8;
        float4 w0 = *(const float4*)wrow;
        float4 w1 = *(const float4*)(wrow + 4);
        float wv[8] = {w0.x, w0.y, w0.z, w0.w, w1.x, w1.y, w1.z, w1.w};
        float ps[4];
#pragma unroll
        for (int r = 0; r < 4; ++r) ps[r] = rdlane(p[r][j], db);
#pragma unroll
        for (int r = 0; r < 4; ++r)
#pragma unroll
          for (int c = 0; c < 8; ++c)
            a2[r][c] = fmaf(ps[r], wv[c], a2[r][c]);
      }
    }
#pragma unroll
    for (int r = 0; r < 4; ++r) {
      const float* px = Xin + (size_t)(n0 + rb + r) * 512 + L * 8;
      float4 x0 = *(const float4*)px;
      float4 x1 = *(const float4*)(px + 4);
      float4 o0, o1;
      o0.x = __fsub_rn(x0.x, a2[r][0]); o0.y = __fsub_rn(x0.y, a2[r][1]);
      o0.z = __fsub_rn(x0.z, a2[r][2]); o0.w = __fsub_rn(x0.w, a2[r][3]);
      o1.x = __fsub_rn(x1.x, a2[r][4]); o1.y = __fsub_rn(x1.y, a2[r][5]);
      o1.z = __fsub_rn(x1.z, a2[r][6]); o1.w = __fsub_rn(x1.w, a2[r][7]);
      float* pxo = Xout + (size_t)(n0 + rb + r) * 512 + L * 8;
      *(float4*)pxo = o0;
      *(float4*)(pxo + 4) = o1;
    }
  }
}

extern "C" void kernel_launch(void* const* d_in, const int* in_sizes, int n_in,
                              void* d_out, int out_size, void* d_ws, size_t ws_size,
                              hipStream_t stream) {
  const float* x  = (const float*)d_in[0];   // [65536,512]
  const float* Cb = (const float*)d_in[1];   // [4,256,512]
  const float* A  = (const float*)d_in[2];   // [4,512,512]
  const float* Wr = (const float*)d_in[3];   // [512,512]
  float* out = (float*)d_out;
  float* ws  = (float*)d_ws;

  float* cpd  = ws;                          // 4*512*256 = 524288 f (2 MB)
  float* xcur = ws + 524288;                 // 65536*512 f (134 MB)

  // keys: fold_in(key(42), i) -> split -> (k_soft = keys[0], k_hard = keys[1])
  uint32_t kh[4][2], ks[4][2];
  for (uint32_t i = 0; i < 4; ++i) {
    uint32_t f0, f1, a0, a1, b0, b1;
    tf2x32(0u, 42u, 0u, i, f0, f1);
    tf2x32(f0, f1, 0u, 0u, a0, a1);   // keys[0] -> k_soft
    tf2x32(f0, f1, 0u, 1u, b0, b1);   // keys[1] -> k_hard
    ks[i][0] = a0; ks[i][1] = a1;
    kh[i][0] = b0; kh[i][1] = b1;
  }

  k_cproj<<<dim3(256), dim3(256), 0, stream>>>(Cb, A, cpd);

  const int NB = NROWS / RPB;  // 4096
  for (int i = 0; i < 4; ++i) {
    const float* Xi = (i == 0) ? x : xcur;
    k_stage<<<dim3(NB), dim3(THR), 0, stream>>>(
        Xi, xcur, A + (size_t)i * DIM * DIM, cpd + (size_t)i * DIM * KCB,
        Cb + (size_t)i * KCB * DIM, Wr, out,
        kh[i][0], kh[i][1], ks[i][0], ks[i][1], i);
  }
}

// Round 5
// 6190.754 us; speedup vs baseline: 1.3356x; 1.0736x over previous
//
#include <hip/hip_runtime.h>
#include <cstdint>
#include <cstddef>
#include <math.h>

#define NROWS 65536
#define DIM   512
#define KCB   256
#define RPW   8     // rows per wave
#define RPB   32    // rows per block (4 waves x 8 rows)
#define THR   256   // threads per block
#define LGS   260   // lgss row stride in floats (16B-aligned, bank-spread)

// ---------------- Threefry-2x32 (jax partitionable; confirmed by R1 bulk match) ----------------
__host__ __device__ __forceinline__ uint32_t tf_rotl(uint32_t x, uint32_t r) {
  return (x << r) | (x >> (32u - r));
}
__host__ __device__ inline void tf2x32(uint32_t k0, uint32_t k1,
                                       uint32_t x0, uint32_t x1,
                                       uint32_t& o0, uint32_t& o1) {
  uint32_t k2 = k0 ^ k1 ^ 0x1BD11BDAu;
  x0 += k0; x1 += k1;
#define TF_R(r) { x0 += x1; x1 = tf_rotl(x1, r); x1 ^= x0; }
  TF_R(13) TF_R(15) TF_R(26) TF_R(6)
  x0 += k1; x1 += k2 + 1u;
  TF_R(17) TF_R(29) TF_R(16) TF_R(24)
  x0 += k2; x1 += k0 + 2u;
  TF_R(13) TF_R(15) TF_R(26) TF_R(6)
  x0 += k0; x1 += k1 + 3u;
  TF_R(17) TF_R(29) TF_R(16) TF_R(24)
  x0 += k1; x1 += k2 + 4u;
  TF_R(13) TF_R(15) TF_R(26) TF_R(6)
  x0 += k2; x1 += k0 + 5u;
#undef TF_R
  o0 = x0; o1 = x1;
}

// f32 gumbel, replicating np-f32: u from jax bits, then -log32(-log32(u)),
// each f32 log obtained by correctly-rounding the f64 log.
__device__ __forceinline__ float gumbel32(uint32_t k0, uint32_t k1, uint32_t j) {
  uint32_t o0, o1;
  tf2x32(k0, k1, 0u, j, o0, o1);
  uint32_t bits = o0 ^ o1;
  float f = __uint_as_float((bits >> 9) | 0x3f800000u) - 1.0f;
  if (f == 0.0f) f = 1.17549435e-38f;
  float t1 = (float)log((double)f);
  float t2 = (float)log((double)(-t1));
  return -t2;
}

__device__ __forceinline__ float exp32cr(float z) {
  return (float)exp((double)z);
}

// wave argmax: f32 value, smaller index wins ties (np first-occurrence)
__device__ __forceinline__ void argmax64(float& v, int& i) {
#pragma unroll
  for (int off = 32; off >= 1; off >>= 1) {
    float ov = __shfl_xor(v, off);
    int   oi = __shfl_xor(i, off);
    if (ov > v || (ov == v && oi < i)) { v = ov; i = oi; }
  }
}

// broadcast one lane's float to all lanes via SGPR (uniform lane index)
__device__ __forceinline__ float rdlane(float v, int lane) {
  return __int_as_float(__builtin_amdgcn_readlane(__float_as_int(v), lane));
}

// ---------------- cpd[i][d][k] = (C_i @ A_i)[k][d], seq-e FMA (BLAS order) ----------------
__global__ __launch_bounds__(256) void k_cproj(const float* __restrict__ C,
                                               const float* __restrict__ A,
                                               float* __restrict__ cpd) {
  const int i = blockIdx.x >> 6;
  const int d0 = (blockIdx.x & 63) * 8;
  const int t = threadIdx.x;          // t = k
  const float* Ai = A + (size_t)i * DIM * DIM;
  const float* Ci = C + (size_t)i * KCB * DIM;
  float acc[8] = {};
  for (int e = 0; e < DIM; ++e) {
    float cv = Ci[(size_t)t * DIM + e];
#pragma unroll
    for (int dd = 0; dd < 8; ++dd)
      acc[dd] = fmaf(cv, Ai[(size_t)e * DIM + d0 + dd], acc[dd]);
  }
#pragma unroll
  for (int dd = 0; dd < 8; ++dd)
    cpd[((size_t)i * DIM + d0 + dd) * KCB + t] = acc[dd];
}

// ---------------- Per-stage, register-resident GEMMs, 8 rows/wave ----------------
// R4 structure (readlane broadcast, zero-LDS GEMM phases) with rows/wave 4->8:
// halves per-FMA load/addressing overhead and per-wave L2 traffic, doubles ILP.
// ph1 remapped to k = 4*lane+s so cpd row d is ONE coalesced b128 load per lane.
// All accumulation orders preserved bit-exact (strict ascending K per output,
// mul/add split in ph1); ph2 body is the R4-verified one (absolute-k LDS layout).
__global__ __launch_bounds__(THR, 3) void k_stage(
    const float* __restrict__ Xin,    // stage input x rows
    float* __restrict__ Xout,         // stage output x rows (stage<3); own-rows in-place safe
    const float* __restrict__ Ai,     // W_att[i] [512][512]
    const float* __restrict__ cpdi,   // cproj^T  [512 d][256 k]
    const float* __restrict__ Cbi,    // codebooks[i] [256][512]
    const float* __restrict__ Wr,     // W_rnn [512][512]
    float* __restrict__ out,
    uint32_t kh0, uint32_t kh1, uint32_t ks0, uint32_t ks1, int stage) {
  __shared__ __align__(16) float lgss[RPB * LGS];   // logits, then exp (in-place)
  __shared__ int selL[RPB]; __shared__ int idxL[RPB]; __shared__ float wsL[RPB];
  const int t = threadIdx.x;
  const int L = t & 63;            // lane
  const int rb = (t >> 6) * RPW;   // wave's rows: rb..rb+7
  const int n0 = blockIdx.x * RPB;

  // load wave's x rows into regs: xr[r][j] = x[n0+rb+r][L*8+j]
  float xr[RPW][8];
#pragma unroll
  for (int r = 0; r < RPW; ++r) {
    const float* px = Xin + (size_t)(n0 + rb + r) * 512 + L * 8;
    float4 a = *(const float4*)px;
    float4 b = *(const float4*)(px + 4);
    xr[r][0] = a.x; xr[r][1] = a.y; xr[r][2] = a.z; xr[r][3] = a.w;
    xr[r][4] = b.x; xr[r][5] = b.y; xr[r][6] = b.z; xr[r][7] = b.w;
  }

  // ph0b: xp[n][d] = seq-e FMA of x[n][e]*A[e][d]; lane L accumulates d = L*8+c.
  float xp[RPW][8];
#pragma unroll
  for (int r = 0; r < RPW; ++r)
#pragma unroll
    for (int c = 0; c < 8; ++c) xp[r][c] = 0.0f;
  for (int eb = 0; eb < 64; ++eb) {
#pragma unroll
    for (int j = 0; j < 8; ++j) {
      const int e = eb * 8 + j;
      const float* arow = Ai + (size_t)e * 512 + L * 8;
      float4 a0 = *(const float4*)arow;
      float4 a1 = *(const float4*)(arow + 4);
      float av[8] = {a0.x, a0.y, a0.z, a0.w, a1.x, a1.y, a1.z, a1.w};
      float xs[RPW];
#pragma unroll
      for (int r = 0; r < RPW; ++r) xs[r] = rdlane(xr[r][j], eb);
#pragma unroll
      for (int r = 0; r < RPW; ++r)
#pragma unroll
        for (int c = 0; c < 8; ++c)
          xp[r][c] = fmaf(xs[r], av[c], xp[r][c]);
    }
  }

  // ph1: logit[n][k] = seq-d (mul,add) of xp[n][d]*cpd[d][k]; lane L owns k = 4L+s.
  // One coalesced b128 of cpd row d per lane; xp broadcast from regs (lane db, reg j).
  float lacc[RPW][4];
#pragma unroll
  for (int r = 0; r < RPW; ++r)
#pragma unroll
    for (int s = 0; s < 4; ++s) lacc[r][s] = 0.0f;
  for (int db = 0; db < 64; ++db) {
#pragma unroll
    for (int j = 0; j < 8; ++j) {
      const int d = db * 8 + j;
      float4 cv = *(const float4*)(cpdi + (size_t)d * 256 + 4 * L);
      float xs[RPW];
#pragma unroll
      for (int r = 0; r < RPW; ++r) xs[r] = rdlane(xp[r][j], db);
#pragma unroll
      for (int r = 0; r < RPW; ++r) {
        lacc[r][0] = __fadd_rn(lacc[r][0], __fmul_rn(xs[r], cv.x));
        lacc[r][1] = __fadd_rn(lacc[r][1], __fmul_rn(xs[r], cv.y));
        lacc[r][2] = __fadd_rn(lacc[r][2], __fmul_rn(xs[r], cv.z));
        lacc[r][3] = __fadd_rn(lacc[r][3], __fmul_rn(xs[r], cv.w));
      }
    }
  }
  // stash logits in LDS at absolute k = 4L+s (float4 per row)
#pragma unroll
  for (int r = 0; r < RPW; ++r)
    *(float4*)&lgss[(rb + r) * LGS + 4 * L] =
        make_float4(lacc[r][0], lacc[r][1], lacc[r][2], lacc[r][3]);
  __syncthreads();

  // ph2: per-row decisions (wave owns 8 rows; lane c owns k = sub*64+c).
  // exp values overwrite logits IN PLACE (same thread, same address — R3/R4-verified).
  {
    const int c = t & 63;
#pragma unroll 1
    for (int rr2 = 0; rr2 < RPW; ++rr2) {
      const int r = (t >> 6) * RPW + rr2;
      const int n = n0 + r;
      const uint32_t jb = (uint32_t)n * 256u;
      float l[4];
#pragma unroll
      for (int sub = 0; sub < 4; ++sub) l[sub] = lgss[r * LGS + sub * 64 + c];
      // idx: first-max over f32 logits
      float bv = l[0]; int bi = c;
#pragma unroll
      for (int sub = 1; sub < 4; ++sub)
        if (l[sub] > bv) { bv = l[sub]; bi = sub * 64 + c; }
      argmax64(bv, bi);
      // hard sel: first-max over (l+g_hard)/0.9f
      float sv = 0.0f; int si = 0;
#pragma unroll
      for (int sub = 0; sub < 4; ++sub) {
        float g = gumbel32(kh0, kh1, jb + (uint32_t)(sub * 64 + c));
        float s = __fdiv_rn(__fadd_rn(l[sub], g), 0.9f);
        if (sub == 0 || s > sv) { sv = s; si = sub * 64 + c; }
      }
      argmax64(sv, si);
      // soft: scores, row max, exp (CR f32)
      float ssv[4];
#pragma unroll
      for (int sub = 0; sub < 4; ++sub) {
        float g = gumbel32(ks0, ks1, jb + (uint32_t)(sub * 64 + c));
        ssv[sub] = __fdiv_rn(__fadd_rn(l[sub], g), 0.9f);
      }
      float m = fmaxf(fmaxf(ssv[0], ssv[1]), fmaxf(ssv[2], ssv[3]));
#pragma unroll
      for (int off = 32; off >= 1; off >>= 1) m = fmaxf(m, __shfl_xor(m, off));
#pragma unroll
      for (int sub = 0; sub < 4; ++sub)
        lgss[r * LGS + sub * 64 + c] = exp32cr(__fsub_rn(ssv[sub], m));
      if (c == 0) { selL[r] = si; idxL[r] = bi; }
    }
  }
  __syncthreads();

  // ph2b: numpy-pairwise softmax denom; 8 threads per row (32 rows).
  // Exact order: per half, acc_j = a[j]+a[8+j]+...+a[120+j] (15 seq adds), then
  // commutative-only shfl_xor(1,2,4) tree = ((r0+r1)+(r2+r3))+((r4+r5)+(r6+r7));
  // S = fadd(half0, half1) in ref order.
  {
    const int r = t >> 3;        // 0..31
    const int j = t & 7;
    const float* a = lgss + r * LGS;
    float acc0 = a[j];
#pragma unroll
    for (int i = 1; i < 16; ++i) acc0 = __fadd_rn(acc0, a[j + 8 * i]);
    float s0 = __fadd_rn(acc0, __shfl_xor(acc0, 1));
    s0 = __fadd_rn(s0, __shfl_xor(s0, 2));
    s0 = __fadd_rn(s0, __shfl_xor(s0, 4));
    float acc1 = a[128 + j];
#pragma unroll
    for (int i = 1; i < 16; ++i) acc1 = __fadd_rn(acc1, a[128 + j + 8 * i]);
    float s1 = __fadd_rn(acc1, __shfl_xor(acc1, 1));
    s1 = __fadd_rn(s1, __shfl_xor(s1, 2));
    s1 = __fadd_rn(s1, __shfl_xor(s1, 4));
    float S = __fadd_rn(s0, s1);
    if (j == 0) {
      const int n = n0 + r;
      int sel = selL[r];
      float wsv = __fdiv_rn(lgss[r * LGS + sel], S);
      wsL[r] = __fadd_rn(__fsub_rn(1.0f, wsv), wsv);
      out[(size_t)NROWS * DIM + (size_t)n * 4 + stage] = (float)idxL[r];
    }
  }
  __syncthreads();

  // ph3: p = fl32(wstar * C[sel][col]) into regs; out_sum RMW (ref add order)
  float p[RPW][8];
#pragma unroll
  for (int r = 0; r < RPW; ++r) {
    const int n = n0 + rb + r;
    const int sel = selL[rb + r];
    const float wv = wsL[rb + r];
    const float* crow = Cbi + (size_t)sel * 512 + L * 8;
    float4 c0 = *(const float4*)crow;
    float4 c1 = *(const float4*)(crow + 4);
    p[r][0] = __fmul_rn(wv, c0.x); p[r][1] = __fmul_rn(wv, c0.y);
    p[r][2] = __fmul_rn(wv, c0.z); p[r][3] = __fmul_rn(wv, c0.w);
    p[r][4] = __fmul_rn(wv, c1.x); p[r][5] = __fmul_rn(wv, c1.y);
    p[r][6] = __fmul_rn(wv, c1.z); p[r][7] = __fmul_rn(wv, c1.w);
    float* orow = out + (size_t)n * 512 + L * 8;
    if (stage == 0) {
      *(float4*)orow = make_float4(p[r][0], p[r][1], p[r][2], p[r][3]);
      *(float4*)(orow + 4) = make_float4(p[r][4], p[r][5], p[r][6], p[r][7]);
    } else {
      float4 o0 = *(const float4*)orow;
      float4 o1 = *(const float4*)(orow + 4);
      o0.x = __fadd_rn(o0.x, p[r][0]); o0.y = __fadd_rn(o0.y, p[r][1]);
      o0.z = __fadd_rn(o0.z, p[r][2]); o0.w = __fadd_rn(o0.w, p[r][3]);
      o1.x = __fadd_rn(o1.x, p[r][4]); o1.y = __fadd_rn(o1.y, p[r][5]);
      o1.z = __fadd_rn(o1.z, p[r][6]); o1.w = __fadd_rn(o1.w, p[r][7]);
      *(float4*)orow = o0;
      *(float4*)(orow + 4) = o1;
    }
  }

  // ph4: x_next = x - p @ W_rnn (seq-d FMA, d strictly ascending); p broadcast
  // from regs via readlane; x reloaded from global (caps live registers).
  if (stage < 3) {
    float a2[RPW][8];
#pragma unroll
    for (int r = 0; r < RPW; ++r)
#pragma unroll
      for (int c = 0; c < 8; ++c) a2[r][c] = 0.0f;
    for (int db = 0; db < 64; ++db) {
#pragma unroll
      for (int j = 0; j < 8; ++j) {
        const int d = db * 8 + j;
        const float* wrow = Wr + (size_t)d * 512 + L * 8;
        float4 w0 = *(const float4*)wrow;
        float4 w1 = *(const float4*)(wrow + 4);
        float wv[8] = {w0.x, w0.y, w0.z, w0.w, w1.x, w1.y, w1.z, w1.w};
        float ps[RPW];
#pragma unroll
        for (int r = 0; r < RPW; ++r) ps[r] = rdlane(p[r][j], db);
#pragma unroll
        for (int r = 0; r < RPW; ++r)
#pragma unroll
          for (int c = 0; c < 8; ++c)
            a2[r][c] = fmaf(ps[r], wv[c], a2[r][c]);
      }
    }
#pragma unroll
    for (int r = 0; r < RPW; ++r) {
      const float* px = Xin + (size_t)(n0 + rb + r) * 512 + L * 8;
      float4 x0 = *(const float4*)px;
      float4 x1 = *(const float4*)(px + 4);
      float4 o0, o1;
      o0.x = __fsub_rn(x0.x, a2[r][0]); o0.y = __fsub_rn(x0.y, a2[r][1]);
      o0.z = __fsub_rn(x0.z, a2[r][2]); o0.w = __fsub_rn(x0.w, a2[r][3]);
      o1.x = __fsub_rn(x1.x, a2[r][4]); o1.y = __fsub_rn(x1.y, a2[r][5]);
      o1.z = __fsub_rn(x1.z, a2[r][6]); o1.w = __fsub_rn(x1.w, a2[r][7]);
      float* pxo = Xout + (size_t)(n0 + rb + r) * 512 + L * 8;
      *(float4*)pxo = o0;
      *(float4*)(pxo + 4) = o1;
    }
  }
}

extern "C" void kernel_launch(void* const* d_in, const int* in_sizes, int n_in,
                              void* d_out, int out_size, void* d_ws, size_t ws_size,
                              hipStream_t stream) {
  const float* x  = (const float*)d_in[0];   // [65536,512]
  const float* Cb = (const float*)d_in[1];   // [4,256,512]
  const float* A  = (const float*)d_in[2];   // [4,512,512]
  const float* Wr = (const float*)d_in[3];   // [512,512]
  float* out = (float*)d_out;
  float* ws  = (float*)d_ws;

  float* cpd  = ws;                          // 4*512*256 = 524288 f (2 MB)
  float* xcur = ws + 524288;                 // 65536*512 f (134 MB)

  // keys: fold_in(key(42), i) -> split -> (k_soft = keys[0], k_hard = keys[1])
  uint32_t kh[4][2], ks[4][2];
  for (uint32_t i = 0; i < 4; ++i) {
    uint32_t f0, f1, a0, a1, b0, b1;
    tf2x32(0u, 42u, 0u, i, f0, f1);
    tf2x32(f0, f1, 0u, 0u, a0, a1);   // keys[0] -> k_soft
    tf2x32(f0, f1, 0u, 1u, b0, b1);   // keys[1] -> k_hard
    ks[i][0] = a0; ks[i][1] = a1;
    kh[i][0] = b0; kh[i][1] = b1;
  }

  k_cproj<<<dim3(256), dim3(256), 0, stream>>>(Cb, A, cpd);

  const int NB = NROWS / RPB;  // 2048
  for (int i = 0; i < 4; ++i) {
    const float* Xi = (i == 0) ? x : xcur;
    k_stage<<<dim3(NB), dim3(THR), 0, stream>>>(
        Xi, xcur, A + (size_t)i * DIM * DIM, cpd + (size_t)i * DIM * KCB,
        Cb + (size_t)i * KCB * DIM, Wr, out,
        kh[i][0], kh[i][1], ks[i][0], ks[i][1], i);
  }
}

// Round 6
// 5117.034 us; speedup vs baseline: 1.6158x; 1.2098x over previous
//
#include <hip/hip_runtime.h>
#include <cstdint>
#include <cstddef>
#include <math.h>

#define NROWS 65536
#define DIM   512
#define KCB   256
#define RPW   8     // rows per wave
#define RPB   32    // rows per block (4 waves x 8 rows)
#define THR   256   // threads per block
#define LGS   260   // shared-buffer row stride in floats (16B-aligned, bank-spread)

// ---------------- Threefry-2x32 (jax partitionable; confirmed by R1 bulk match) ----------------
__host__ __device__ __forceinline__ uint32_t tf_rotl(uint32_t x, uint32_t r) {
  return (x << r) | (x >> (32u - r));
}
__host__ __device__ inline void tf2x32(uint32_t k0, uint32_t k1,
                                       uint32_t x0, uint32_t x1,
                                       uint32_t& o0, uint32_t& o1) {
  uint32_t k2 = k0 ^ k1 ^ 0x1BD11BDAu;
  x0 += k0; x1 += k1;
#define TF_R(r) { x0 += x1; x1 = tf_rotl(x1, r); x1 ^= x0; }
  TF_R(13) TF_R(15) TF_R(26) TF_R(6)
  x0 += k1; x1 += k2 + 1u;
  TF_R(17) TF_R(29) TF_R(16) TF_R(24)
  x0 += k2; x1 += k0 + 2u;
  TF_R(13) TF_R(15) TF_R(26) TF_R(6)
  x0 += k0; x1 += k1 + 3u;
  TF_R(17) TF_R(29) TF_R(16) TF_R(24)
  x0 += k1; x1 += k2 + 4u;
  TF_R(13) TF_R(15) TF_R(26) TF_R(6)
  x0 += k2; x1 += k0 + 5u;
#undef TF_R
  o0 = x0; o1 = x1;
}

// f32 gumbel, replicating np-f32: u from jax bits, then -log32(-log32(u)),
// each f32 log obtained by correctly-rounding the f64 log.
__device__ __forceinline__ float gumbel32(uint32_t k0, uint32_t k1, uint32_t j) {
  uint32_t o0, o1;
  tf2x32(k0, k1, 0u, j, o0, o1);
  uint32_t bits = o0 ^ o1;
  float f = __uint_as_float((bits >> 9) | 0x3f800000u) - 1.0f;
  if (f == 0.0f) f = 1.17549435e-38f;
  float t1 = (float)log((double)f);
  float t2 = (float)log((double)(-t1));
  return -t2;
}

__device__ __forceinline__ float exp32cr(float z) {
  return (float)exp((double)z);
}

// wave argmax: f32 value, smaller index wins ties (np first-occurrence)
__device__ __forceinline__ void argmax64(float& v, int& i) {
#pragma unroll
  for (int off = 32; off >= 1; off >>= 1) {
    float ov = __shfl_xor(v, off);
    int   oi = __shfl_xor(i, off);
    if (ov > v || (ov == v && oi < i)) { v = ov; i = oi; }
  }
}

// broadcast one lane's float to all lanes via SGPR (uniform lane index)
__device__ __forceinline__ float rdlane(float v, int lane) {
  return __int_as_float(__builtin_amdgcn_readlane(__float_as_int(v), lane));
}

// ---------------- cpd[i][d][k] = (C_i @ A_i)[k][d], seq-e FMA (BLAS order) ----------------
__global__ __launch_bounds__(256) void k_cproj(const float* __restrict__ C,
                                               const float* __restrict__ A,
                                               float* __restrict__ cpd) {
  const int i = blockIdx.x >> 6;
  const int d0 = (blockIdx.x & 63) * 8;
  const int t = threadIdx.x;          // t = k
  const float* Ai = A + (size_t)i * DIM * DIM;
  const float* Ci = C + (size_t)i * KCB * DIM;
  float acc[8] = {};
  for (int e = 0; e < DIM; ++e) {
    float cv = Ci[(size_t)t * DIM + e];
#pragma unroll
    for (int dd = 0; dd < 8; ++dd)
      acc[dd] = fmaf(cv, Ai[(size_t)e * DIM + d0 + dd], acc[dd]);
  }
#pragma unroll
  for (int dd = 0; dd < 8; ++dd)
    cpd[((size_t)i * DIM + d0 + dd) * KCB + t] = acc[dd];
}

// ---------------- Per-stage: LDS-broadcast GEMMs, 8 rows/wave, small reg footprint ----------------
// R5's readlane broadcast forced 64-reg wave arrays (xr, p) -> 168-reg alloc (84V+84A),
// 2.5 waves/SIMD. R6 broadcasts the sequential-K operand via UNIFORM-ADDRESS ds_read
// (hardware broadcast, conflict-free): x and p live in a 33KB LDS buffer (halves),
// overlaid with the logits/exp buffer (disjoint lifetimes). Register peak ~110 ->
// 4 waves/SIMD x 4 blocks/CU. All arithmetic sequences bit-identical to R5 (verified):
// strict ascending K per output, mul/add split in ph1, verified ph2/ph2b bodies.
__global__ __launch_bounds__(THR, 4) void k_stage(
    const float* __restrict__ Xin,    // stage input x rows
    float* __restrict__ Xout,         // stage output x rows (stage<3); own-rows in-place safe
    const float* __restrict__ Ai,     // W_att[i] [512][512]
    const float* __restrict__ cpdi,   // cproj^T  [512 d][256 k]
    const float* __restrict__ Cbi,    // codebooks[i] [256][512]
    const float* __restrict__ Wr,     // W_rnn [512][512]
    float* __restrict__ out,
    uint32_t kh0, uint32_t kh1, uint32_t ks0, uint32_t ks1, int stage) {
  __shared__ __align__(16) float sh[RPB * LGS];   // x-half / logits+exp / p-half
  __shared__ int selL[RPB]; __shared__ int idxL[RPB]; __shared__ float wsL[RPB];
  const int t = threadIdx.x;
  const int L = t & 63;            // lane
  const int rb = (t >> 6) * RPW;   // wave's rows: rb..rb+7
  const int n0 = blockIdx.x * RPB;

  // ph0b: xp[n][d] = seq-e FMA of x[n][e]*A[e][d]; lane L owns d = L*8+c.
  // x staged in LDS halves; broadcast via uniform ds_read (same addr all lanes).
  float xp[RPW][8];
#pragma unroll
  for (int r = 0; r < RPW; ++r)
#pragma unroll
    for (int c = 0; c < 8; ++c) xp[r][c] = 0.0f;

#pragma unroll 1
  for (int h = 0; h < 2; ++h) {
    // stage x[:, h*256 .. h*256+256) for all 32 block rows (coalesced b128)
#pragma unroll
    for (int q = 0; q < 8; ++q) {
      const int idx = q * 256 + t;
      const int row = idx >> 6, c4 = idx & 63;
      *(float4*)&sh[row * LGS + c4 * 4] =
          *(const float4*)&Xin[(size_t)(n0 + row) * 512 + h * 256 + c4 * 4];
    }
    __syncthreads();
    for (int eh = 0; eh < 256; eh += 2) {
      const int e = h * 256 + eh;
      const float* ar0 = Ai + (size_t)e * 512 + L * 8;
      float4 a00 = *(const float4*)ar0;
      float4 a01 = *(const float4*)(ar0 + 4);
      float4 a10 = *(const float4*)(ar0 + 512);
      float4 a11 = *(const float4*)(ar0 + 516);
      float av0[8] = {a00.x, a00.y, a00.z, a00.w, a01.x, a01.y, a01.z, a01.w};
      float av1[8] = {a10.x, a10.y, a10.z, a10.w, a11.x, a11.y, a11.z, a11.w};
      float2 xs[RPW];
#pragma unroll
      for (int r = 0; r < RPW; ++r)
        xs[r] = *(const float2*)&sh[(rb + r) * LGS + eh];   // uniform: broadcast
#pragma unroll
      for (int r = 0; r < RPW; ++r) {
#pragma unroll
        for (int c = 0; c < 8; ++c) xp[r][c] = fmaf(xs[r].x, av0[c], xp[r][c]);
#pragma unroll
        for (int c = 0; c < 8; ++c) xp[r][c] = fmaf(xs[r].y, av1[c], xp[r][c]);
      }
    }
    __syncthreads();   // half consumed before overwrite / before lgss reuse
  }

  // ph1: logit[n][k] = seq-d (mul,add) of xp[n][d]*cpd[d][k]; lane L owns k = 4L+s.
  // One coalesced b128 of cpd row d per lane; xp broadcast from regs (lane db, reg j).
  float lacc[RPW][4];
#pragma unroll
  for (int r = 0; r < RPW; ++r)
#pragma unroll
    for (int s = 0; s < 4; ++s) lacc[r][s] = 0.0f;
  for (int db = 0; db < 64; ++db) {
#pragma unroll
    for (int j = 0; j < 8; ++j) {
      const int d = db * 8 + j;
      float4 cv = *(const float4*)(cpdi + (size_t)d * 256 + 4 * L);
      float xs[RPW];
#pragma unroll
      for (int r = 0; r < RPW; ++r) xs[r] = rdlane(xp[r][j], db);
#pragma unroll
      for (int r = 0; r < RPW; ++r) {
        lacc[r][0] = __fadd_rn(lacc[r][0], __fmul_rn(xs[r], cv.x));
        lacc[r][1] = __fadd_rn(lacc[r][1], __fmul_rn(xs[r], cv.y));
        lacc[r][2] = __fadd_rn(lacc[r][2], __fmul_rn(xs[r], cv.z));
        lacc[r][3] = __fadd_rn(lacc[r][3], __fmul_rn(xs[r], cv.w));
      }
    }
  }
  // stash logits at absolute k = 4L+s (float4 per row)
#pragma unroll
  for (int r = 0; r < RPW; ++r)
    *(float4*)&sh[(rb + r) * LGS + 4 * L] =
        make_float4(lacc[r][0], lacc[r][1], lacc[r][2], lacc[r][3]);
  __syncthreads();

  // ph2: per-row decisions (wave owns 8 rows; lane c owns k = sub*64+c).
  // exp values overwrite logits IN PLACE (same thread, same address — R3/R4/R5-verified).
  {
    const int c = t & 63;
#pragma unroll 1
    for (int rr2 = 0; rr2 < RPW; ++rr2) {
      const int r = (t >> 6) * RPW + rr2;
      const int n = n0 + r;
      const uint32_t jb = (uint32_t)n * 256u;
      float l[4];
#pragma unroll
      for (int sub = 0; sub < 4; ++sub) l[sub] = sh[r * LGS + sub * 64 + c];
      // idx: first-max over f32 logits
      float bv = l[0]; int bi = c;
#pragma unroll
      for (int sub = 1; sub < 4; ++sub)
        if (l[sub] > bv) { bv = l[sub]; bi = sub * 64 + c; }
      argmax64(bv, bi);
      // hard sel: first-max over (l+g_hard)/0.9f
      float sv = 0.0f; int si = 0;
#pragma unroll
      for (int sub = 0; sub < 4; ++sub) {
        float g = gumbel32(kh0, kh1, jb + (uint32_t)(sub * 64 + c));
        float s = __fdiv_rn(__fadd_rn(l[sub], g), 0.9f);
        if (sub == 0 || s > sv) { sv = s; si = sub * 64 + c; }
      }
      argmax64(sv, si);
      // soft: scores, row max, exp (CR f32)
      float ssv[4];
#pragma unroll
      for (int sub = 0; sub < 4; ++sub) {
        float g = gumbel32(ks0, ks1, jb + (uint32_t)(sub * 64 + c));
        ssv[sub] = __fdiv_rn(__fadd_rn(l[sub], g), 0.9f);
      }
      float m = fmaxf(fmaxf(ssv[0], ssv[1]), fmaxf(ssv[2], ssv[3]));
#pragma unroll
      for (int off = 32; off >= 1; off >>= 1) m = fmaxf(m, __shfl_xor(m, off));
#pragma unroll
      for (int sub = 0; sub < 4; ++sub)
        sh[r * LGS + sub * 64 + c] = exp32cr(__fsub_rn(ssv[sub], m));
      if (c == 0) { selL[r] = si; idxL[r] = bi; }
    }
  }
  __syncthreads();

  // ph2b: numpy-pairwise softmax denom; 8 threads per row (32 rows).
  // Exact order: per half, acc_j = a[j]+a[8+j]+...+a[120+j] (15 seq adds), then
  // commutative-only shfl_xor(1,2,4) tree = ((r0+r1)+(r2+r3))+((r4+r5)+(r6+r7));
  // S = fadd(half0, half1) in ref order.  (R5-verified)
  {
    const int r = t >> 3;        // 0..31
    const int j = t & 7;
    const float* a = sh + r * LGS;
    float acc0 = a[j];
#pragma unroll
    for (int i = 1; i < 16; ++i) acc0 = __fadd_rn(acc0, a[j + 8 * i]);
    float s0 = __fadd_rn(acc0, __shfl_xor(acc0, 1));
    s0 = __fadd_rn(s0, __shfl_xor(s0, 2));
    s0 = __fadd_rn(s0, __shfl_xor(s0, 4));
    float acc1 = a[128 + j];
#pragma unroll
    for (int i = 1; i < 16; ++i) acc1 = __fadd_rn(acc1, a[128 + j + 8 * i]);
    float s1 = __fadd_rn(acc1, __shfl_xor(acc1, 1));
    s1 = __fadd_rn(s1, __shfl_xor(s1, 2));
    s1 = __fadd_rn(s1, __shfl_xor(s1, 4));
    float S = __fadd_rn(s0, s1);
    if (j == 0) {
      const int n = n0 + r;
      int sel = selL[r];
      float wsv = __fdiv_rn(sh[r * LGS + sel], S);
      wsL[r] = __fadd_rn(__fsub_rn(1.0f, wsv), wsv);
      out[(size_t)NROWS * DIM + (size_t)n * 4 + stage] = (float)idxL[r];
    }
  }
  __syncthreads();

  // ph3/ph4 in column halves: p = fl32(wstar * C[sel][col]) (4 cols/lane/half),
  // out_sum RMW (per-col, ref order), p-half staged in sh (overlays dead exp buf),
  // ph4 broadcasts p via uniform ds_read; a2 accumulates d = 0..511 ascending.
  float a2[RPW][8];
  if (stage < 3) {
#pragma unroll
    for (int r = 0; r < RPW; ++r)
#pragma unroll
      for (int c = 0; c < 8; ++c) a2[r][c] = 0.0f;
  }
#pragma unroll 1
  for (int h = 0; h < 2; ++h) {
    float4 p4[RPW];
#pragma unroll
    for (int r = 0; r < RPW; ++r) {
      const int n = n0 + rb + r;
      const int sel = selL[rb + r];
      const float wv = wsL[rb + r];
      float4 cv = *(const float4*)(Cbi + (size_t)sel * 512 + h * 256 + 4 * L);
      p4[r].x = __fmul_rn(wv, cv.x); p4[r].y = __fmul_rn(wv, cv.y);
      p4[r].z = __fmul_rn(wv, cv.z); p4[r].w = __fmul_rn(wv, cv.w);
      float* orow = out + (size_t)n * 512 + h * 256 + 4 * L;
      if (stage == 0) {
        *(float4*)orow = p4[r];
      } else {
        float4 o = *(const float4*)orow;
        o.x = __fadd_rn(o.x, p4[r].x); o.y = __fadd_rn(o.y, p4[r].y);
        o.z = __fadd_rn(o.z, p4[r].z); o.w = __fadd_rn(o.w, p4[r].w);
        *(float4*)orow = o;
      }
    }
    if (stage < 3) {
      __syncthreads();   // exp buf (h=0) / prev p-half (h=1) fully consumed
#pragma unroll
      for (int r = 0; r < RPW; ++r)
        *(float4*)&sh[(rb + r) * LGS + 4 * L] = p4[r];
      __syncthreads();
      for (int dl = 0; dl < 256; dl += 2) {
        const int d = h * 256 + dl;
        const float* wr0 = Wr + (size_t)d * 512 + L * 8;
        float4 w00 = *(const float4*)wr0;
        float4 w01 = *(const float4*)(wr0 + 4);
        float4 w10 = *(const float4*)(wr0 + 512);
        float4 w11 = *(const float4*)(wr0 + 516);
        float wv0[8] = {w00.x, w00.y, w00.z, w00.w, w01.x, w01.y, w01.z, w01.w};
        float wv1[8] = {w10.x, w10.y, w10.z, w10.w, w11.x, w11.y, w11.z, w11.w};
        float2 ps[RPW];
#pragma unroll
        for (int r = 0; r < RPW; ++r)
          ps[r] = *(const float2*)&sh[(rb + r) * LGS + dl];   // uniform: broadcast
#pragma unroll
        for (int r = 0; r < RPW; ++r) {
#pragma unroll
          for (int c = 0; c < 8; ++c) a2[r][c] = fmaf(ps[r].x, wv0[c], a2[r][c]);
#pragma unroll
          for (int c = 0; c < 8; ++c) a2[r][c] = fmaf(ps[r].y, wv1[c], a2[r][c]);
        }
      }
    }
  }

  // x_next = x - p@Wr, write to global (own rows; in-place safe)
  if (stage < 3) {
#pragma unroll
    for (int r = 0; r < RPW; ++r) {
      const float* px = Xin + (size_t)(n0 + rb + r) * 512 + L * 8;
      float4 x0 = *(const float4*)px;
      float4 x1 = *(const float4*)(px + 4);
      float4 o0, o1;
      o0.x = __fsub_rn(x0.x, a2[r][0]); o0.y = __fsub_rn(x0.y, a2[r][1]);
      o0.z = __fsub_rn(x0.z, a2[r][2]); o0.w = __fsub_rn(x0.w, a2[r][3]);
      o1.x = __fsub_rn(x1.x, a2[r][4]); o1.y = __fsub_rn(x1.y, a2[r][5]);
      o1.z = __fsub_rn(x1.z, a2[r][6]); o1.w = __fsub_rn(x1.w, a2[r][7]);
      float* pxo = Xout + (size_t)(n0 + rb + r) * 512 + L * 8;
      *(float4*)pxo = o0;
      *(float4*)(pxo + 4) = o1;
    }
  }
}

extern "C" void kernel_launch(void* const* d_in, const int* in_sizes, int n_in,
                              void* d_out, int out_size, void* d_ws, size_t ws_size,
                              hipStream_t stream) {
  const float* x  = (const float*)d_in[0];   // [65536,512]
  const float* Cb = (const float*)d_in[1];   // [4,256,512]
  const float* A  = (const float*)d_in[2];   // [4,512,512]
  const float* Wr = (const float*)d_in[3];   // [512,512]
  float* out = (float*)d_out;
  float* ws  = (float*)d_ws;

  float* cpd  = ws;                          // 4*512*256 = 524288 f (2 MB)
  float* xcur = ws + 524288;                 // 65536*512 f (134 MB)

  // keys: fold_in(key(42), i) -> split -> (k_soft = keys[0], k_hard = keys[1])
  uint32_t kh[4][2], ks[4][2];
  for (uint32_t i = 0; i < 4; ++i) {
    uint32_t f0, f1, a0, a1, b0, b1;
    tf2x32(0u, 42u, 0u, i, f0, f1);
    tf2x32(f0, f1, 0u, 0u, a0, a1);   // keys[0] -> k_soft
    tf2x32(f0, f1, 0u, 1u, b0, b1);   // keys[1] -> k_hard
    ks[i][0] = a0; ks[i][1] = a1;
    kh[i][0] = b0; kh[i][1] = b1;
  }

  k_cproj<<<dim3(256), dim3(256), 0, stream>>>(Cb, A, cpd);

  const int NB = NROWS / RPB;  // 2048
  for (int i = 0; i < 4; ++i) {
    const float* Xi = (i == 0) ? x : xcur;
    k_stage<<<dim3(NB), dim3(THR), 0, stream>>>(
        Xi, xcur, A + (size_t)i * DIM * DIM, cpd + (size_t)i * DIM * KCB,
        Cb + (size_t)i * KCB * DIM, Wr, out,
        kh[i][0], kh[i][1], ks[i][0], ks[i][1], i);
  }
}